// Round 3
// baseline (477.275 us; speedup 1.0000x reference)
//
#include <hip/hip_runtime.h>
#include <hip/hip_bf16.h>
#include <cstdint>
#include <cstddef>

#define B_ 4
#define S_ 2048
#define E_ 1024
#define H_ 16
#define D_ 64
#define NEG_BIG (-1e30f)
#define SC2 0.18033688011112043f   /* 0.125 * log2(e) */

typedef __bf16 bf16x8 __attribute__((ext_vector_type(8)));
typedef __bf16 bf16x4v __attribute__((ext_vector_type(4)));
typedef float f32x4 __attribute__((ext_vector_type(4)));
typedef float f32x16 __attribute__((ext_vector_type(16)));

__device__ __forceinline__ void async_copy16(void* lds, const void* g) {
  __builtin_amdgcn_global_load_lds(
      (const __attribute__((address_space(1))) void*)g,
      (__attribute__((address_space(3))) void*)lds, 16, 0, 0);
}

__device__ __forceinline__ float bfu2f(unsigned short u) {
  unsigned v = ((unsigned)u) << 16;
  float f;
  __builtin_memcpy(&f, &v, 4);
  return f;
}
__device__ __forceinline__ unsigned short f2bfu(float f) {
  __hip_bfloat16 h = __float2bfloat16(f);  // RNE
  unsigned short u;
  __builtin_memcpy(&u, &h, 2);
  return u;
}
__device__ __forceinline__ unsigned pk2(float a, float b) {
  return (unsigned)f2bfu(a) | ((unsigned)f2bfu(b) << 16);
}

// swap hi 32 lanes of a with lo 32 lanes of b (v_permlane32_swap_b32)
__device__ __forceinline__ void pl32swap(unsigned& a, unsigned& b) {
#if defined(__has_builtin)
#if __has_builtin(__builtin_amdgcn_permlane32_swap)
  typedef int i32x2 __attribute__((ext_vector_type(2)));
  i32x2 r = __builtin_amdgcn_permlane32_swap((int)a, (int)b, false, false);
  a = (unsigned)r[0];
  b = (unsigned)r[1];
  return;
#else
  asm("v_permlane32_swap_b32 %0, %1" : "+v"(a), "+v"(b));
  return;
#endif
#else
  asm("v_permlane32_swap_b32 %0, %1" : "+v"(a), "+v"(b));
#endif
}

// ---------------- dtype probe (proven) ----------------
__global__ __launch_bounds__(256) void probe_dtype(
    const unsigned short* __restrict__ xr, int* __restrict__ flagp) {
  __shared__ int cnt;
  if (threadIdx.x == 0) cnt = 0;
  __syncthreads();
  int bad = 0;
  for (int i = 0; i < 32; ++i) {
    unsigned short u = xr[(threadIdx.x * 32 + i) * 2];
    int e = (u >> 7) & 0xFF;
    if (e == 0xFF || e >= 0x90 || (e != 0 && e <= 0x60)) bad++;
  }
  atomicAdd(&cnt, bad);
  __syncthreads();
  if (threadIdx.x == 0) {
    flagp[0] = (cnt > 512) ? 0 : 1;  // 0=fp32, 1=bf16
    flagp[1] = 1;                    // all-ones-mask flag, cleared by mask_bias
  }
}

__global__ __launch_bounds__(256) void convert_to_f32(
    const void* __restrict__ in, float* __restrict__ out,
    const int* __restrict__ flagp, int n) {
  int i = blockIdx.x * blockDim.x + threadIdx.x;
  if (i >= n) return;
  out[i] = (*flagp == 0) ? ((const float*)in)[i]
                         : bfu2f(((const unsigned short*)in)[i]);
}

// x (fp32|bf16) -> bf16, vectorized 8 elems/thread
__global__ __launch_bounds__(256) void conv_x_bf16(
    const void* __restrict__ in, long long off,
    unsigned short* __restrict__ out,
    const int* __restrict__ flagp, int n8) {
  int i = blockIdx.x * 256 + threadIdx.x;
  if (i >= n8) return;
  if (*flagp == 0) {
    const float* p = (const float*)in + off + (size_t)i * 8;
    float4 a = *(const float4*)p;
    float4 b = *(const float4*)(p + 4);
    uint4 o = make_uint4(pk2(a.x, a.y), pk2(a.z, a.w), pk2(b.x, b.y), pk2(b.z, b.w));
    *(uint4*)(out + (size_t)i * 8) = o;
  } else {
    const unsigned short* p = (const unsigned short*)in + off + (size_t)i * 8;
    *(uint4*)(out + (size_t)i * 8) = *(const uint4*)p;
  }
}

// pad mask -> additive bias (0 / -1e30); also detect all-ones mask
__global__ __launch_bounds__(256) void mask_bias(
    const int* __restrict__ am, float* __restrict__ mb,
    int* __restrict__ flagp, int n) {
  int i = blockIdx.x * blockDim.x + threadIdx.x;
  if (i < n) {
    int a = am[i];
    mb[i] = a ? 0.f : NEG_BIG;
    if (a == 0) atomicAnd(flagp + 1, 0);
  }
}

// transpose + convert: out_bf16[C][R] = in[R][C]   (proven)
__global__ __launch_bounds__(256) void transpose_conv(
    const void* __restrict__ in, unsigned short* __restrict__ out,
    const int* __restrict__ flagp, int R, int C) {
  __shared__ unsigned short t[32][33];
  const int flag = *flagp;
  const int c0 = blockIdx.x * 32, r0 = blockIdx.y * 32;
  const int lc = threadIdx.x & 31, lr = threadIdx.x >> 5;
  for (int i = 0; i < 4; ++i) {
    int r = lr + i * 8;
    size_t idx = (size_t)(r0 + r) * C + c0 + lc;
    t[r][lc] = (flag == 0) ? f2bfu(((const float*)in)[idx])
                           : ((const unsigned short*)in)[idx];
  }
  __syncthreads();
  for (int i = 0; i < 4; ++i) {
    int r = lr + i * 8;
    out[(size_t)(c0 + r) * R + r0 + lc] = t[lc][r];
  }
}

// -------- unified bf16 GEMM: C = A @ Bt^T + bias -------------------------
// 128x128 tile, BK=64 (32 MFMA per barrier pair), both operands async
// global->LDS, 8-chunk XOR swizzle (ch ^ row&7) for conflict-free
// ds_read_b128.  1D grid, XCD-chunked m-tiles for L2 A-panel reuse.
// outmode 0: bf16 out.  outmode 1: dtype by flag (fp32|bf16).
__global__ __launch_bounds__(256) void gemm_bb(
    const __hip_bfloat16* __restrict__ A,
    const __hip_bfloat16* __restrict__ Bt,
    const float* __restrict__ bias,
    const int* __restrict__ flagp, int outmode,
    void* __restrict__ Cv, long long coff,
    int M, int N, int K) {
  __shared__ __align__(16) __hip_bfloat16 As[128 * 64];
  __shared__ __align__(16) __hip_bfloat16 Bs[128 * 64];
  const int flag = *flagp;
  const int tid = threadIdx.x;
  const int lin = blockIdx.x;
  const int mtiles = M >> 7;
  const int mloc = mtiles >> 3;                 // m-tiles per XCD (pow2)
  const int msh = 31 - __builtin_clz(mloc);
  const int xcd = lin & 7, idx = lin >> 3;
  const int m0 = (xcd * mloc + (idx & (mloc - 1))) << 7;
  const int n0 = (idx >> msh) << 7;
  const int w = tid >> 6, lane = tid & 63;
  const int wm = (w & 1) * 64, wn = (w >> 1) * 64;
  const int lm = lane & 15, kg = lane >> 4;

  f32x4 acc[4][4] = {};

  for (int k0 = 0; k0 < K; k0 += 64) {
    __syncthreads();   // readers of LDS done
    #pragma unroll
    for (int c = 0; c < 4; ++c) {
      int o = tid * 16 + c * 4096;
      int row = o >> 7, chp = (o >> 4) & 7;
      int gch = chp ^ (row & 7);
      async_copy16((char*)As + o, (const char*)(A + (size_t)(m0 + row) * K + k0 + gch * 8));
      async_copy16((char*)Bs + o, (const char*)(Bt + (size_t)(n0 + row) * K + k0 + gch * 8));
    }
    __syncthreads();   // staging landed (compiler drains vmcnt before barrier)
    #pragma unroll
    for (int kk = 0; kk < 2; ++kk) {
      bf16x8 af[4], bff[4];
      #pragma unroll
      for (int t = 0; t < 4; ++t) {
        int rt = wm + t * 16 + lm;
        int ch = (kk * 4 + kg) ^ (rt & 7);
        af[t] = *(const bf16x8*)(As + rt * 64 + ch * 8);
        int rb = wn + t * 16 + lm;
        int chb = (kk * 4 + kg) ^ (rb & 7);
        bff[t] = *(const bf16x8*)(Bs + rb * 64 + chb * 8);
      }
      #pragma unroll
      for (int tm = 0; tm < 4; ++tm)
        #pragma unroll
        for (int tn = 0; tn < 4; ++tn)
          acc[tm][tn] = __builtin_amdgcn_mfma_f32_16x16x32_bf16(af[tm], bff[tn], acc[tm][tn], 0, 0, 0);
    }
  }

  const bool f32out = (outmode != 0 && flag == 0);
  for (int tn = 0; tn < 4; ++tn) {
    int col = n0 + wn + tn * 16 + lm;
    float bv = bias[col];
    for (int tm = 0; tm < 4; ++tm) {
      int rbase = m0 + wm + tm * 16 + kg * 4;
      for (int r = 0; r < 4; ++r) {
        float v = acc[tm][tn][r] + bv;
        size_t oidx = (size_t)coff + (size_t)(rbase + r) * N + col;
        if (f32out) ((float*)Cv)[oidx] = v;
        else        ((unsigned short*)Cv)[oidx] = f2bfu(v);
      }
    }
  }
}

// -------- causal flash attention v6 ----------------------------------------
// 128 threads (2 waves), 64 q/block (32 q/wave), 32-key subtiles.
// K direct global->VGPR (pipelined ka/kb parity); V via LDS (transposed,
// double-buffered).  2048 blocks, LDS-capped 8 blocks/CU co-resident
// (16 waves/CU) -- 2x the wave-level parallelism of the 4-wave version.
// XCD-chunked so all q-tiles of one (b,h) share an XCD's L2 K/V panel.
#define VSTR 72
__device__ __forceinline__ void attn_subtile(
    int j0s, int wq_min, int wq_max, int qg, int allones,
    const char* kbyte, const float* mbrow,
    uint4& kc0, uint4& kc1, uint4& kc2, uint4& kc3,
    uint4& kn0, uint4& kn1, uint4& kn2, uint4& kn3,
    const bf16x8* bq, const __hip_bfloat16* VTb, int hi,
    float& mrow, float& plocal, f32x16& o0, f32x16& o1) {
  if (j0s > wq_max) return;
  {  // prefetch next subtile's K fragments (registers)
    const int jn = j0s + 32;
    if (jn <= wq_max) {
      const char* kp = kbyte + (size_t)jn * 6144;
      kn0 = *(const uint4*)(kp);
      kn1 = *(const uint4*)(kp + 32);
      kn2 = *(const uint4*)(kp + 64);
      kn3 = *(const uint4*)(kp + 96);
    }
  }
  bf16x8 a0, a1, a2, a3;
  __builtin_memcpy(&a0, &kc0, 16);
  __builtin_memcpy(&a1, &kc1, 16);
  __builtin_memcpy(&a2, &kc2, 16);
  __builtin_memcpy(&a3, &kc3, 16);

  // ---- S^T = K · Q^T ----
  f32x16 sacc = {};
  __builtin_amdgcn_s_setprio(1);
  sacc = __builtin_amdgcn_mfma_f32_32x32x16_bf16(a0, bq[0], sacc, 0, 0, 0);
  sacc = __builtin_amdgcn_mfma_f32_32x32x16_bf16(a1, bq[1], sacc, 0, 0, 0);
  sacc = __builtin_amdgcn_mfma_f32_32x32x16_bf16(a2, bq[2], sacc, 0, 0, 0);
  sacc = __builtin_amdgcn_mfma_f32_32x32x16_bf16(a3, bq[3], sacc, 0, 0, 0);
  __builtin_amdgcn_s_setprio(0);

  // ---- mask + max ----
  float mt = NEG_BIG;
  const bool needc = (j0s + 31 > wq_min);
  if (allones) {
    if (needc) {
      #pragma unroll
      for (int r = 0; r < 16; ++r) {
        int key = j0s + (r & 3) + 8 * (r >> 2) + 4 * hi;
        float v = (key <= qg) ? sacc[r] : NEG_BIG;
        sacc[r] = v;
        mt = fmaxf(mt, v);
      }
    } else {
      #pragma unroll
      for (int r = 0; r < 16; ++r) mt = fmaxf(mt, sacc[r]);
    }
    mt *= SC2;  // scores stay raw; scale folded into exp fma
  } else {
    #pragma unroll
    for (int rr = 0; rr < 4; ++rr) {
      float4 mb4 = *(const float4*)(mbrow + j0s + rr * 8 + hi * 4);
      const float* mp = (const float*)&mb4;
      #pragma unroll
      for (int i = 0; i < 4; ++i) {
        int r = rr * 4 + i;
        int key = j0s + i + 8 * rr + 4 * hi;
        float v = fmaf(sacc[r], SC2, mp[i]);
        if (needc) v = (key <= qg) ? v : NEG_BIG;
        sacc[r] = v;
        mt = fmaxf(mt, v);
      }
    }
  }
  mt = fmaxf(mt, __shfl_xor(mt, 32));

  // ---- defer-max rescale (THR=8, log2 domain) ----
  if (!__all(mt <= mrow + 8.f)) {
    float mn = fmaxf(mrow, mt);
    float a = __builtin_exp2f(mrow - mn);
    plocal *= a;
    #pragma unroll
    for (int r = 0; r < 16; ++r) { o0[r] *= a; o1[r] *= a; }
    mrow = mn;
  }

  // ---- exp + pack ----
  const float sfac = allones ? SC2 : 1.0f;
  float psl = 0.f;
  unsigned pk[8];
  #pragma unroll
  for (int r2 = 0; r2 < 8; ++r2) {
    float p0 = __builtin_exp2f(fmaf(sacc[2 * r2],     sfac, -mrow));
    float p1 = __builtin_exp2f(fmaf(sacc[2 * r2 + 1], sfac, -mrow));
    psl += p0 + p1;
    pk[r2] = pk2(p0, p1);
  }
  plocal += psl;

  // ---- in-register P exchange ----
  pl32swap(pk[0], pk[2]);
  pl32swap(pk[1], pk[3]);
  pl32swap(pk[4], pk[6]);
  pl32swap(pk[5], pk[7]);

  // ---- O^T += V^T · P ----
  __builtin_amdgcn_s_setprio(1);
  #pragma unroll
  for (int ks = 0; ks < 2; ++ks) {
    uint4 t = make_uint4(pk[ks * 4 + 0], pk[ks * 4 + 1],
                         pk[ks * 4 + 2], pk[ks * 4 + 3]);
    bf16x8 bp;
    __builtin_memcpy(&bp, &t, 16);
    bf16x8 av0 = *(const bf16x8*)(VTb + ks * 16);
    bf16x8 av1 = *(const bf16x8*)(VTb + 32 * VSTR + ks * 16);
    o0 = __builtin_amdgcn_mfma_f32_32x32x16_bf16(av0, bp, o0, 0, 0, 0);
    o1 = __builtin_amdgcn_mfma_f32_32x32x16_bf16(av1, bp, o1, 0, 0, 0);
  }
  __builtin_amdgcn_s_setprio(0);
}

__global__ __launch_bounds__(128, 4) void attn_flash(
    const __hip_bfloat16* __restrict__ qkv,  // [bsz*S][3072]
    const float* __restrict__ mbias,         // [bsz*S] 0 / -1e30
    const int* __restrict__ flags,           // flags[1]: mask all-ones
    __hip_bfloat16* __restrict__ outp) {     // [bsz*S][1024]
  __shared__ __align__(16) __hip_bfloat16 VT[2][64 * VSTR]; // [d][key]

  const int tid = threadIdx.x;
  // XCD-chunked: XCD k owns bh in [k*bhloc,(k+1)*bhloc), all 32 q-tiles;
  // within XCD, heavy q-tiles first (LPT).
  const int lin = blockIdx.x;
  const int nbh = gridDim.x >> 5;          // 32 q-tiles of 64 rows
  const int bhloc = nbh >> 3;
  const int bsh = 31 - __builtin_clz(bhloc);
  const int xcd = lin & 7, idx = lin >> 3;
  const int bh = xcd * bhloc + (idx & (bhloc - 1));
  const int bx = idx >> bsh;
  const int qt = 31 - bx;                  // LPT: heavy first
  const int b = bh >> 4, h = bh & 15;
  const int q0 = qt * 64;
  const size_t rowbase = (size_t)b * S_;
  const int w = tid >> 6, lane = tid & 63;
  const int l31 = lane & 31, hi = lane >> 5;
  const int qg = q0 + w * 32 + l31;
  const int wq_min = q0 + w * 32, wq_max = wq_min + 31;
  const int allones = flags[1];
  const float* mbrow = mbias + rowbase;

  // per-lane K base: row l31, d-offset hi*8 (fragment kc at +kc*32B)
  const char* kbyte = (const char*)(qkv + (rowbase + l31) * 3072 + 1024 + h * 64 + hi * 8);

  // Q fragments: lane holds Q[qg][kc*16 + hi*8 + e]
  bf16x8 bq[4];
  {
    const __hip_bfloat16* qp = qkv + (rowbase + qg) * 3072 + h * 64 + hi * 8;
    bq[0] = *(const bf16x8*)(qp);
    bq[1] = *(const bf16x8*)(qp + 16);
    bq[2] = *(const bf16x8*)(qp + 32);
    bq[3] = *(const bf16x8*)(qp + 48);
  }

  const int jmax = qt;   // 64-key tiles 0..qt

  // prologue: K subtile 0 into ka; V tile 0 into VT[0]
  uint4 ka0, ka1, ka2, ka3, kb0, kb1, kb2, kb3;
  ka0 = *(const uint4*)(kbyte);
  ka1 = *(const uint4*)(kbyte + 32);
  ka2 = *(const uint4*)(kbyte + 64);
  ka3 = *(const uint4*)(kbyte + 96);
  {
    const __hip_bfloat16* vp = qkv + (rowbase + lane) * 3072 + 2048 + h * 64 + w * 32;
    uint4 v0 = *(const uint4*)(vp);
    uint4 v1 = *(const uint4*)(vp + 8);
    uint4 v2 = *(const uint4*)(vp + 16);
    uint4 v3 = *(const uint4*)(vp + 24);
    const __hip_bfloat16* p0 = (const __hip_bfloat16*)&v0;
    const __hip_bfloat16* p1 = (const __hip_bfloat16*)&v1;
    const __hip_bfloat16* p2 = (const __hip_bfloat16*)&v2;
    const __hip_bfloat16* p3 = (const __hip_bfloat16*)&v3;
    #pragma unroll
    for (int e = 0; e < 8; ++e) {
      VT[0][(w * 32 + e) * VSTR + lane] = p0[e];
      VT[0][(w * 32 + 8 + e) * VSTR + lane] = p1[e];
      VT[0][(w * 32 + 16 + e) * VSTR + lane] = p2[e];
      VT[0][(w * 32 + 24 + e) * VSTR + lane] = p3[e];
    }
  }

  float mrow = NEG_BIG, plocal = 0.f;
  f32x16 o0 = {}, o1 = {};   // O^T: col q=l31, row d = dblk*32 + (r&3)+8*(r>>2)+4*hi
  int buf = 0;

  for (int j = 0; j <= jmax; ++j) {
    __syncthreads();  // VT[buf] staged; prior readers of nbuf done
    const int nbuf = buf ^ 1;
    const int j0 = j * 64;
    const bool pre = (j < jmax);
    uint4 vva, vvb, vvc, vvd;
    if (pre) {
      const __hip_bfloat16* vp = qkv + (rowbase + j0 + 64 + lane) * 3072 + 2048 + h * 64 + w * 32;
      vva = *(const uint4*)(vp);
      vvb = *(const uint4*)(vp + 8);
      vvc = *(const uint4*)(vp + 16);
      vvd = *(const uint4*)(vp + 24);
    }
    const __hip_bfloat16* vb0 = VT[buf] + l31 * VSTR + hi * 8;

    attn_subtile(j0, wq_min, wq_max, qg, allones, kbyte, mbrow,
                 ka0, ka1, ka2, ka3, kb0, kb1, kb2, kb3,
                 bq, vb0, hi, mrow, plocal, o0, o1);
    attn_subtile(j0 + 32, wq_min, wq_max, qg, allones, kbyte, mbrow,
                 kb0, kb1, kb2, kb3, ka0, ka1, ka2, ka3,
                 bq, vb0 + 32, hi, mrow, plocal, o0, o1);

    if (pre) {  // finish staging of nbuf (VT)
      const __hip_bfloat16* p0 = (const __hip_bfloat16*)&vva;
      const __hip_bfloat16* p1 = (const __hip_bfloat16*)&vvb;
      const __hip_bfloat16* p2 = (const __hip_bfloat16*)&vvc;
      const __hip_bfloat16* p3 = (const __hip_bfloat16*)&vvd;
      #pragma unroll
      for (int e = 0; e < 8; ++e) {
        VT[nbuf][(w * 32 + e) * VSTR + lane] = p0[e];
        VT[nbuf][(w * 32 + 8 + e) * VSTR + lane] = p1[e];
        VT[nbuf][(w * 32 + 16 + e) * VSTR + lane] = p2[e];
        VT[nbuf][(w * 32 + 24 + e) * VSTR + lane] = p3[e];
      }
    }
    buf = nbuf;
  }

  {  // epilogue: reduce l across hi halves, divide, store
    float l = plocal + __shfl_xor(plocal, 32);
    float linv = (l > 0.f) ? 1.f / l : 0.f;
    __hip_bfloat16* ob = outp + (rowbase + qg) * 1024 + h * 64;
    #pragma unroll
    for (int rr = 0; rr < 4; ++rr) {
      bf16x4v ov;
      ov[0] = (__bf16)(o0[rr * 4 + 0] * linv);
      ov[1] = (__bf16)(o0[rr * 4 + 1] * linv);
      ov[2] = (__bf16)(o0[rr * 4 + 2] * linv);
      ov[3] = (__bf16)(o0[rr * 4 + 3] * linv);
      *(bf16x4v*)(ob + rr * 8 + hi * 4) = ov;
      bf16x4v ow;
      ow[0] = (__bf16)(o1[rr * 4 + 0] * linv);
      ow[1] = (__bf16)(o1[rr * 4 + 1] * linv);
      ow[2] = (__bf16)(o1[rr * 4 + 2] * linv);
      ow[3] = (__bf16)(o1[rr * 4 + 3] * linv);
      *(bf16x4v*)(ob + 32 + rr * 8 + hi * 4) = ow;
    }
  }
}

extern "C" void kernel_launch(void* const* d_in, const int* in_sizes, int n_in,
                              void* d_out, int out_size, void* d_ws, size_t ws_size,
                              hipStream_t stream) {
  const bool merged = (ws_size >= (80ull << 20));
  char* ws = (char*)d_ws;
  int*            flag   = (int*)ws;
  float*          bq     = (float*)(ws + 1024);
  float*          bp     = (float*)(ws + 16384);
  float*          mbias  = (float*)(ws + 32768);
  unsigned short* WqkvTu = (unsigned short*)(ws + 65536);
  unsigned short* WprojTu= (unsigned short*)(ws + 65536 + 6291456);
  char*           big    = ws + 65536 + 8388608;
  __hip_bfloat16* qkv    = (__hip_bfloat16*)big;
  // attno region doubles as xbf (x pre-converted to bf16): xbf is consumed
  // by GEMM1 before attn writes attno over it.
  char*           anx    = big + (merged ? 50331648u : 12582912u);
  __hip_bfloat16* attno  = (__hip_bfloat16*)anx;
  unsigned short* xbf    = (unsigned short*)anx;

  probe_dtype<<<1, 256, 0, stream>>>((const unsigned short*)d_in[0], flag);
  convert_to_f32<<<12, 256, 0, stream>>>(d_in[3], bq, flag, 3072);
  convert_to_f32<<<4, 256, 0, stream>>>(d_in[5], bp, flag, 1024);
  mask_bias<<<(B_ * S_) / 256, 256, 0, stream>>>((const int*)d_in[1], mbias, flag, B_ * S_);
  transpose_conv<<<dim3(96, 32), 256, 0, stream>>>(d_in[2], WqkvTu, flag, 1024, 3072);
  transpose_conv<<<dim3(32, 32), 256, 0, stream>>>(d_in[4], WprojTu, flag, 1024, 1024);

  const int nchunk = merged ? 1 : B_;
  const int bsz = merged ? B_ : 1;
  const int Mc = bsz * S_;
  for (int c = 0; c < nchunk; ++c) {
    long long off = (long long)c * S_ * E_;
    conv_x_bf16<<<dim3((Mc * 1024) / 2048), 256, 0, stream>>>(
        d_in[0], off, xbf, flag, (Mc * 1024) / 8);
    gemm_bb<<<dim3((Mc / 128) * (3072 / 128)), 256, 0, stream>>>(
        (const __hip_bfloat16*)xbf, (const __hip_bfloat16*)WqkvTu, bq, flag, 0,
        qkv, 0, Mc, 3072, 1024);
    attn_flash<<<dim3((S_ / 64) * (bsz * H_)), 128, 0, stream>>>(
        qkv, mbias + (size_t)c * S_, flag, attno);
    gemm_bb<<<dim3((Mc / 128) * (1024 / 128)), 256, 0, stream>>>(
        attno, (const __hip_bfloat16*)WprojTu, bp, flag, 1,
        d_out, off, Mc, 1024, 1024);
  }
}

// Round 4
// 307.020 us; speedup vs baseline: 1.5545x; 1.5545x over previous
//
#include <hip/hip_runtime.h>
#include <hip/hip_bf16.h>
#include <cstdint>
#include <cstddef>

#define B_ 4
#define S_ 2048
#define E_ 1024
#define H_ 16
#define D_ 64
#define NEG_BIG (-1e30f)
#define SC2 0.18033688011112043f   /* 0.125 * log2(e) */

typedef __bf16 bf16x8 __attribute__((ext_vector_type(8)));
typedef __bf16 bf16x4v __attribute__((ext_vector_type(4)));
typedef float f32x4 __attribute__((ext_vector_type(4)));
typedef float f32x16 __attribute__((ext_vector_type(16)));

__device__ __forceinline__ void async_copy16(void* lds, const void* g) {
  __builtin_amdgcn_global_load_lds(
      (const __attribute__((address_space(1))) void*)g,
      (__attribute__((address_space(3))) void*)lds, 16, 0, 0);
}

__device__ __forceinline__ float bfu2f(unsigned short u) {
  unsigned v = ((unsigned)u) << 16;
  float f;
  __builtin_memcpy(&f, &v, 4);
  return f;
}
__device__ __forceinline__ unsigned short f2bfu(float f) {
  __hip_bfloat16 h = __float2bfloat16(f);  // RNE
  unsigned short u;
  __builtin_memcpy(&u, &h, 2);
  return u;
}
__device__ __forceinline__ unsigned pk2(float a, float b) {
  return (unsigned)f2bfu(a) | ((unsigned)f2bfu(b) << 16);
}

// swap hi 32 lanes of a with lo 32 lanes of b (v_permlane32_swap_b32)
__device__ __forceinline__ void pl32swap(unsigned& a, unsigned& b) {
#if defined(__has_builtin)
#if __has_builtin(__builtin_amdgcn_permlane32_swap)
  typedef int i32x2 __attribute__((ext_vector_type(2)));
  i32x2 r = __builtin_amdgcn_permlane32_swap((int)a, (int)b, false, false);
  a = (unsigned)r[0];
  b = (unsigned)r[1];
  return;
#else
  asm("v_permlane32_swap_b32 %0, %1" : "+v"(a), "+v"(b));
  return;
#endif
#else
  asm("v_permlane32_swap_b32 %0, %1" : "+v"(a), "+v"(b));
#endif
}

// ---------------- dtype probe (proven) ----------------
__global__ __launch_bounds__(256) void probe_dtype(
    const unsigned short* __restrict__ xr, int* __restrict__ flagp) {
  __shared__ int cnt;
  if (threadIdx.x == 0) cnt = 0;
  __syncthreads();
  int bad = 0;
  for (int i = 0; i < 32; ++i) {
    unsigned short u = xr[(threadIdx.x * 32 + i) * 2];
    int e = (u >> 7) & 0xFF;
    if (e == 0xFF || e >= 0x90 || (e != 0 && e <= 0x60)) bad++;
  }
  atomicAdd(&cnt, bad);
  __syncthreads();
  if (threadIdx.x == 0) {
    flagp[0] = (cnt > 512) ? 0 : 1;  // 0=fp32, 1=bf16
    flagp[1] = 1;                    // all-ones-mask flag, cleared by mask_bias
  }
}

__global__ __launch_bounds__(256) void convert_to_f32(
    const void* __restrict__ in, float* __restrict__ out,
    const int* __restrict__ flagp, int n) {
  int i = blockIdx.x * blockDim.x + threadIdx.x;
  if (i >= n) return;
  out[i] = (*flagp == 0) ? ((const float*)in)[i]
                         : bfu2f(((const unsigned short*)in)[i]);
}

// x (fp32|bf16) -> bf16, vectorized 8 elems/thread
__global__ __launch_bounds__(256) void conv_x_bf16(
    const void* __restrict__ in, long long off,
    unsigned short* __restrict__ out,
    const int* __restrict__ flagp, int n8) {
  int i = blockIdx.x * 256 + threadIdx.x;
  if (i >= n8) return;
  if (*flagp == 0) {
    const float* p = (const float*)in + off + (size_t)i * 8;
    float4 a = *(const float4*)p;
    float4 b = *(const float4*)(p + 4);
    uint4 o = make_uint4(pk2(a.x, a.y), pk2(a.z, a.w), pk2(b.x, b.y), pk2(b.z, b.w));
    *(uint4*)(out + (size_t)i * 8) = o;
  } else {
    const unsigned short* p = (const unsigned short*)in + off + (size_t)i * 8;
    *(uint4*)(out + (size_t)i * 8) = *(const uint4*)p;
  }
}

// pad mask -> additive bias (0 / -1e30); also detect all-ones mask
__global__ __launch_bounds__(256) void mask_bias(
    const int* __restrict__ am, float* __restrict__ mb,
    int* __restrict__ flagp, int n) {
  int i = blockIdx.x * blockDim.x + threadIdx.x;
  if (i < n) {
    int a = am[i];
    mb[i] = a ? 0.f : NEG_BIG;
    if (a == 0) atomicAnd(flagp + 1, 0);
  }
}

// transpose + convert: out_bf16[C][R] = in[R][C]   (proven)
__global__ __launch_bounds__(256) void transpose_conv(
    const void* __restrict__ in, unsigned short* __restrict__ out,
    const int* __restrict__ flagp, int R, int C) {
  __shared__ unsigned short t[32][33];
  const int flag = *flagp;
  const int c0 = blockIdx.x * 32, r0 = blockIdx.y * 32;
  const int lc = threadIdx.x & 31, lr = threadIdx.x >> 5;
  for (int i = 0; i < 4; ++i) {
    int r = lr + i * 8;
    size_t idx = (size_t)(r0 + r) * C + c0 + lc;
    t[r][lc] = (flag == 0) ? f2bfu(((const float*)in)[idx])
                           : ((const unsigned short*)in)[idx];
  }
  __syncthreads();
  for (int i = 0; i < 4; ++i) {
    int r = lr + i * 8;
    out[(size_t)(c0 + r) * R + r0 + lc] = t[lc][r];
  }
}

// -------- unified bf16 GEMM: C = A @ Bt^T + bias -------------------------
// 128x128 tile, BK=64 (32 MFMA per barrier pair), both operands async
// global->LDS, 8-chunk XOR swizzle (ch ^ row&7) for conflict-free
// ds_read_b128.  1D grid, XCD-chunked m-tiles for L2 A-panel reuse.
// outmode 0: bf16 out.  outmode 1: dtype by flag (fp32|bf16).
__global__ __launch_bounds__(256) void gemm_bb(
    const __hip_bfloat16* __restrict__ A,
    const __hip_bfloat16* __restrict__ Bt,
    const float* __restrict__ bias,
    const int* __restrict__ flagp, int outmode,
    void* __restrict__ Cv, long long coff,
    int M, int N, int K) {
  __shared__ __align__(16) __hip_bfloat16 As[128 * 64];
  __shared__ __align__(16) __hip_bfloat16 Bs[128 * 64];
  const int flag = *flagp;
  const int tid = threadIdx.x;
  const int lin = blockIdx.x;
  const int mtiles = M >> 7;
  const int mloc = mtiles >> 3;                 // m-tiles per XCD (pow2)
  const int msh = 31 - __builtin_clz(mloc);
  const int xcd = lin & 7, idx = lin >> 3;
  const int m0 = (xcd * mloc + (idx & (mloc - 1))) << 7;
  const int n0 = (idx >> msh) << 7;
  const int w = tid >> 6, lane = tid & 63;
  const int wm = (w & 1) * 64, wn = (w >> 1) * 64;
  const int lm = lane & 15, kg = lane >> 4;

  f32x4 acc[4][4] = {};

  for (int k0 = 0; k0 < K; k0 += 64) {
    __syncthreads();   // readers of LDS done
    #pragma unroll
    for (int c = 0; c < 4; ++c) {
      int o = tid * 16 + c * 4096;
      int row = o >> 7, chp = (o >> 4) & 7;
      int gch = chp ^ (row & 7);
      async_copy16((char*)As + o, (const char*)(A + (size_t)(m0 + row) * K + k0 + gch * 8));
      async_copy16((char*)Bs + o, (const char*)(Bt + (size_t)(n0 + row) * K + k0 + gch * 8));
    }
    __syncthreads();   // staging landed (compiler drains vmcnt before barrier)
    #pragma unroll
    for (int kk = 0; kk < 2; ++kk) {
      bf16x8 af[4], bff[4];
      #pragma unroll
      for (int t = 0; t < 4; ++t) {
        int rt = wm + t * 16 + lm;
        int ch = (kk * 4 + kg) ^ (rt & 7);
        af[t] = *(const bf16x8*)(As + rt * 64 + ch * 8);
        int rb = wn + t * 16 + lm;
        int chb = (kk * 4 + kg) ^ (rb & 7);
        bff[t] = *(const bf16x8*)(Bs + rb * 64 + chb * 8);
      }
      #pragma unroll
      for (int tm = 0; tm < 4; ++tm)
        #pragma unroll
        for (int tn = 0; tn < 4; ++tn)
          acc[tm][tn] = __builtin_amdgcn_mfma_f32_16x16x32_bf16(af[tm], bff[tn], acc[tm][tn], 0, 0, 0);
    }
  }

  const bool f32out = (outmode != 0 && flag == 0);
  for (int tn = 0; tn < 4; ++tn) {
    int col = n0 + wn + tn * 16 + lm;
    float bv = bias[col];
    for (int tm = 0; tm < 4; ++tm) {
      int rbase = m0 + wm + tm * 16 + kg * 4;
      for (int r = 0; r < 4; ++r) {
        float v = acc[tm][tn][r] + bv;
        size_t oidx = (size_t)coff + (size_t)(rbase + r) * N + col;
        if (f32out) ((float*)Cv)[oidx] = v;
        else        ((unsigned short*)Cv)[oidx] = f2bfu(v);
      }
    }
  }
}

// -------- causal flash attention v5 (proven R2 config) ---------------------
// 256 threads (4 waves), 128 q/block (32 q/wave), 32-key subtiles.
// K fetched DIRECTLY global->VGPR as MFMA A-fragments, software-pipelined
// one subtile ahead (ka/kb parity) -- no K LDS, no K barrier coupling.
// Only V goes through LDS (transposed, double-buffered, 1 barrier/tile).
// XCD-chunked block swizzle keeps each (b,h)'s K/V panels L2-hot.
// NOTE: do NOT shrink blocks / raise launch_bounds min-waves: the 128-thread
// (128,4) variant spilled (~470 MB scratch writes, 2.5x slower).
#define VSTR 72
__device__ __forceinline__ void attn_subtile(
    int j0s, int wq_min, int wq_max, int qg, int allones,
    const char* kbyte, const float* mbrow,
    uint4& kc0, uint4& kc1, uint4& kc2, uint4& kc3,
    uint4& kn0, uint4& kn1, uint4& kn2, uint4& kn3,
    const bf16x8* bq, const __hip_bfloat16* VTb, int hi,
    float& mrow, float& plocal, f32x16& o0, f32x16& o1) {
  if (j0s > wq_max) return;
  {  // prefetch next subtile's K fragments (registers)
    const int jn = j0s + 32;
    if (jn <= wq_max) {
      const char* kp = kbyte + (size_t)jn * 6144;
      kn0 = *(const uint4*)(kp);
      kn1 = *(const uint4*)(kp + 32);
      kn2 = *(const uint4*)(kp + 64);
      kn3 = *(const uint4*)(kp + 96);
    }
  }
  bf16x8 a0, a1, a2, a3;
  __builtin_memcpy(&a0, &kc0, 16);
  __builtin_memcpy(&a1, &kc1, 16);
  __builtin_memcpy(&a2, &kc2, 16);
  __builtin_memcpy(&a3, &kc3, 16);

  // ---- S^T = K · Q^T ----
  f32x16 sacc = {};
  __builtin_amdgcn_s_setprio(1);
  sacc = __builtin_amdgcn_mfma_f32_32x32x16_bf16(a0, bq[0], sacc, 0, 0, 0);
  sacc = __builtin_amdgcn_mfma_f32_32x32x16_bf16(a1, bq[1], sacc, 0, 0, 0);
  sacc = __builtin_amdgcn_mfma_f32_32x32x16_bf16(a2, bq[2], sacc, 0, 0, 0);
  sacc = __builtin_amdgcn_mfma_f32_32x32x16_bf16(a3, bq[3], sacc, 0, 0, 0);
  __builtin_amdgcn_s_setprio(0);

  // ---- mask + max ----
  float mt = NEG_BIG;
  const bool needc = (j0s + 31 > wq_min);
  if (allones) {
    if (needc) {
      #pragma unroll
      for (int r = 0; r < 16; ++r) {
        int key = j0s + (r & 3) + 8 * (r >> 2) + 4 * hi;
        float v = (key <= qg) ? sacc[r] : NEG_BIG;
        sacc[r] = v;
        mt = fmaxf(mt, v);
      }
    } else {
      #pragma unroll
      for (int r = 0; r < 16; ++r) mt = fmaxf(mt, sacc[r]);
    }
    mt *= SC2;  // scores stay raw; scale folded into exp fma
  } else {
    #pragma unroll
    for (int rr = 0; rr < 4; ++rr) {
      float4 mb4 = *(const float4*)(mbrow + j0s + rr * 8 + hi * 4);
      const float* mp = (const float*)&mb4;
      #pragma unroll
      for (int i = 0; i < 4; ++i) {
        int r = rr * 4 + i;
        int key = j0s + i + 8 * rr + 4 * hi;
        float v = fmaf(sacc[r], SC2, mp[i]);
        if (needc) v = (key <= qg) ? v : NEG_BIG;
        sacc[r] = v;
        mt = fmaxf(mt, v);
      }
    }
  }
  mt = fmaxf(mt, __shfl_xor(mt, 32));

  // ---- defer-max rescale (THR=8, log2 domain) ----
  if (!__all(mt <= mrow + 8.f)) {
    float mn = fmaxf(mrow, mt);
    float a = __builtin_exp2f(mrow - mn);
    plocal *= a;
    #pragma unroll
    for (int r = 0; r < 16; ++r) { o0[r] *= a; o1[r] *= a; }
    mrow = mn;
  }

  // ---- exp + pack ----
  const float sfac = allones ? SC2 : 1.0f;
  float psl = 0.f;
  unsigned pk[8];
  #pragma unroll
  for (int r2 = 0; r2 < 8; ++r2) {
    float p0 = __builtin_exp2f(fmaf(sacc[2 * r2],     sfac, -mrow));
    float p1 = __builtin_exp2f(fmaf(sacc[2 * r2 + 1], sfac, -mrow));
    psl += p0 + p1;
    pk[r2] = pk2(p0, p1);
  }
  plocal += psl;

  // ---- in-register P exchange ----
  pl32swap(pk[0], pk[2]);
  pl32swap(pk[1], pk[3]);
  pl32swap(pk[4], pk[6]);
  pl32swap(pk[5], pk[7]);

  // ---- O^T += V^T · P ----
  __builtin_amdgcn_s_setprio(1);
  #pragma unroll
  for (int ks = 0; ks < 2; ++ks) {
    uint4 t = make_uint4(pk[ks * 4 + 0], pk[ks * 4 + 1],
                         pk[ks * 4 + 2], pk[ks * 4 + 3]);
    bf16x8 bp;
    __builtin_memcpy(&bp, &t, 16);
    bf16x8 av0 = *(const bf16x8*)(VTb + ks * 16);
    bf16x8 av1 = *(const bf16x8*)(VTb + 32 * VSTR + ks * 16);
    o0 = __builtin_amdgcn_mfma_f32_32x32x16_bf16(av0, bp, o0, 0, 0, 0);
    o1 = __builtin_amdgcn_mfma_f32_32x32x16_bf16(av1, bp, o1, 0, 0, 0);
  }
  __builtin_amdgcn_s_setprio(0);
}

__global__ __launch_bounds__(256, 3) void attn_flash(
    const __hip_bfloat16* __restrict__ qkv,  // [bsz*S][3072]
    const float* __restrict__ mbias,         // [bsz*S] 0 / -1e30
    const int* __restrict__ flags,           // flags[1]: mask all-ones
    __hip_bfloat16* __restrict__ outp) {     // [bsz*S][1024]
  __shared__ __align__(16) __hip_bfloat16 VT[2][64 * VSTR]; // [d][key]

  const int tid = threadIdx.x;
  // XCD-chunked swizzle: XCD k owns bh in [k*bhloc,(k+1)*bhloc), all q-tiles;
  // within XCD, heavy q-tiles (large qt) dispatched first (LPT).
  const int lin = blockIdx.x;
  const int nbh = gridDim.x >> 4;          // 16 q-blocks of 128 rows
  const int bhloc = nbh >> 3;
  const int bsh = 31 - __builtin_clz(bhloc);
  const int xcd = lin & 7, idx = lin >> 3;
  const int bh = xcd * bhloc + (idx & (bhloc - 1));
  const int bx = idx >> bsh;
  const int qt = 15 - bx;                  // LPT: heavy first
  const int b = bh >> 4, h = bh & 15;
  const int q0 = qt * 128;
  const size_t rowbase = (size_t)b * S_;
  const int w = tid >> 6, lane = tid & 63;
  const int l31 = lane & 31, hi = lane >> 5;
  const int qg = q0 + w * 32 + l31;
  const int wq_min = q0 + w * 32, wq_max = wq_min + 31;
  const int allones = flags[1];
  const float* mbrow = mbias + rowbase;

  // per-lane K base: row l31, d-offset hi*8 (fragment kc at +kc*32B)
  const char* kbyte = (const char*)(qkv + (rowbase + l31) * 3072 + 1024 + h * 64 + hi * 8);

  // Q fragments: lane holds Q[qg][kc*16 + hi*8 + e]
  bf16x8 bq[4];
  {
    const __hip_bfloat16* qp = qkv + (rowbase + qg) * 3072 + h * 64 + hi * 8;
    bq[0] = *(const bf16x8*)(qp);
    bq[1] = *(const bf16x8*)(qp + 16);
    bq[2] = *(const bf16x8*)(qp + 32);
    bq[3] = *(const bf16x8*)(qp + 48);
  }

  const int jmax = 2 * qt + 1;

  // prologue: K subtile 0 into ka; V tile 0 into VT[0]
  uint4 ka0, ka1, ka2, ka3, kb0, kb1, kb2, kb3;
  ka0 = *(const uint4*)(kbyte);
  ka1 = *(const uint4*)(kbyte + 32);
  ka2 = *(const uint4*)(kbyte + 64);
  ka3 = *(const uint4*)(kbyte + 96);
  {
    const __hip_bfloat16* vp = qkv + (rowbase + lane) * 3072 + 2048 + h * 64 + w * 16;
    uint4 v0 = *(const uint4*)(vp);
    uint4 v1 = *(const uint4*)(vp + 8);
    const __hip_bfloat16* p0 = (const __hip_bfloat16*)&v0;
    const __hip_bfloat16* p1 = (const __hip_bfloat16*)&v1;
    #pragma unroll
    for (int e = 0; e < 8; ++e) {
      VT[0][(w * 16 + e) * VSTR + lane] = p0[e];
      VT[0][(w * 16 + 8 + e) * VSTR + lane] = p1[e];
    }
  }

  float mrow = NEG_BIG, plocal = 0.f;
  f32x16 o0 = {}, o1 = {};   // O^T: col q=l31, row d = dblk*32 + (r&3)+8*(r>>2)+4*hi
  int buf = 0;

  for (int j = 0; j <= jmax; ++j) {
    __syncthreads();  // VT[buf] staged; prior readers of nbuf done
    const int nbuf = buf ^ 1;
    const int j0 = j * 64;
    const bool pre = (j < jmax);
    uint4 vva, vvb;
    if (pre) {
      const __hip_bfloat16* vp = qkv + (rowbase + j0 + 64 + lane) * 3072 + 2048 + h * 64 + w * 16;
      vva = *(const uint4*)(vp);
      vvb = *(const uint4*)(vp + 8);
    }
    const __hip_bfloat16* vb0 = VT[buf] + l31 * VSTR + hi * 8;

    attn_subtile(j0, wq_min, wq_max, qg, allones, kbyte, mbrow,
                 ka0, ka1, ka2, ka3, kb0, kb1, kb2, kb3,
                 bq, vb0, hi, mrow, plocal, o0, o1);
    attn_subtile(j0 + 32, wq_min, wq_max, qg, allones, kbyte, mbrow,
                 kb0, kb1, kb2, kb3, ka0, ka1, ka2, ka3,
                 bq, vb0 + 32, hi, mrow, plocal, o0, o1);

    if (pre) {  // finish staging of nbuf (VT)
      const __hip_bfloat16* p0 = (const __hip_bfloat16*)&vva;
      const __hip_bfloat16* p1 = (const __hip_bfloat16*)&vvb;
      #pragma unroll
      for (int e = 0; e < 8; ++e) {
        VT[nbuf][(w * 16 + e) * VSTR + lane] = p0[e];
        VT[nbuf][(w * 16 + 8 + e) * VSTR + lane] = p1[e];
      }
    }
    buf = nbuf;
  }

  {  // epilogue: reduce l across hi halves, divide, store
    float l = plocal + __shfl_xor(plocal, 32);
    float linv = (l > 0.f) ? 1.f / l : 0.f;
    __hip_bfloat16* ob = outp + (rowbase + qg) * 1024 + h * 64;
    #pragma unroll
    for (int rr = 0; rr < 4; ++rr) {
      bf16x4v ov;
      ov[0] = (__bf16)(o0[rr * 4 + 0] * linv);
      ov[1] = (__bf16)(o0[rr * 4 + 1] * linv);
      ov[2] = (__bf16)(o0[rr * 4 + 2] * linv);
      ov[3] = (__bf16)(o0[rr * 4 + 3] * linv);
      *(bf16x4v*)(ob + rr * 8 + hi * 4) = ov;
      bf16x4v ow;
      ow[0] = (__bf16)(o1[rr * 4 + 0] * linv);
      ow[1] = (__bf16)(o1[rr * 4 + 1] * linv);
      ow[2] = (__bf16)(o1[rr * 4 + 2] * linv);
      ow[3] = (__bf16)(o1[rr * 4 + 3] * linv);
      *(bf16x4v*)(ob + 32 + rr * 8 + hi * 4) = ow;
    }
  }
}

extern "C" void kernel_launch(void* const* d_in, const int* in_sizes, int n_in,
                              void* d_out, int out_size, void* d_ws, size_t ws_size,
                              hipStream_t stream) {
  const bool merged = (ws_size >= (80ull << 20));
  char* ws = (char*)d_ws;
  int*            flag   = (int*)ws;
  float*          bq     = (float*)(ws + 1024);
  float*          bp     = (float*)(ws + 16384);
  float*          mbias  = (float*)(ws + 32768);
  unsigned short* WqkvTu = (unsigned short*)(ws + 65536);
  unsigned short* WprojTu= (unsigned short*)(ws + 65536 + 6291456);
  char*           big    = ws + 65536 + 8388608;
  __hip_bfloat16* qkv    = (__hip_bfloat16*)big;
  // attno region doubles as xbf (x pre-converted to bf16): xbf is consumed
  // by GEMM1 before attn writes attno over it.
  char*           anx    = big + (merged ? 50331648u : 12582912u);
  __hip_bfloat16* attno  = (__hip_bfloat16*)anx;
  unsigned short* xbf    = (unsigned short*)anx;

  probe_dtype<<<1, 256, 0, stream>>>((const unsigned short*)d_in[0], flag);
  convert_to_f32<<<12, 256, 0, stream>>>(d_in[3], bq, flag, 3072);
  convert_to_f32<<<4, 256, 0, stream>>>(d_in[5], bp, flag, 1024);
  mask_bias<<<(B_ * S_) / 256, 256, 0, stream>>>((const int*)d_in[1], mbias, flag, B_ * S_);
  transpose_conv<<<dim3(96, 32), 256, 0, stream>>>(d_in[2], WqkvTu, flag, 1024, 3072);
  transpose_conv<<<dim3(32, 32), 256, 0, stream>>>(d_in[4], WprojTu, flag, 1024, 1024);

  const int nchunk = merged ? 1 : B_;
  const int bsz = merged ? B_ : 1;
  const int Mc = bsz * S_;
  for (int c = 0; c < nchunk; ++c) {
    long long off = (long long)c * S_ * E_;
    conv_x_bf16<<<dim3((Mc * 1024) / 2048), 256, 0, stream>>>(
        d_in[0], off, xbf, flag, (Mc * 1024) / 8);
    gemm_bb<<<dim3((Mc / 128) * (3072 / 128)), 256, 0, stream>>>(
        (const __hip_bfloat16*)xbf, (const __hip_bfloat16*)WqkvTu, bq, flag, 0,
        qkv, 0, Mc, 3072, 1024);
    attn_flash<<<dim3((S_ / 128) * (bsz * H_)), 256, 0, stream>>>(
        qkv, mbias + (size_t)c * S_, flag, attno);
    gemm_bb<<<dim3((Mc / 128) * (1024 / 128)), 256, 0, stream>>>(
        attno, (const __hip_bfloat16*)WprojTu, bp, flag, 1,
        d_out, off, Mc, 1024, 1024);
  }
}

// Round 6
// 299.531 us; speedup vs baseline: 1.5934x; 1.0250x over previous
//
#include <hip/hip_runtime.h>
#include <hip/hip_bf16.h>
#include <cstdint>
#include <cstddef>

#define B_ 4
#define S_ 2048
#define E_ 1024
#define H_ 16
#define D_ 64
#define NEG_BIG (-1e30f)
#define SC2 0.18033688011112043f   /* 0.125 * log2(e) */

typedef __bf16 bf16x8 __attribute__((ext_vector_type(8)));
typedef __bf16 bf16x4v __attribute__((ext_vector_type(4)));
typedef float f32x4 __attribute__((ext_vector_type(4)));
typedef float f32x16 __attribute__((ext_vector_type(16)));

__device__ __forceinline__ void async_copy16(void* lds, const void* g) {
  __builtin_amdgcn_global_load_lds(
      (const __attribute__((address_space(1))) void*)g,
      (__attribute__((address_space(3))) void*)lds, 16, 0, 0);
}

__device__ __forceinline__ float bfu2f(unsigned short u) {
  unsigned v = ((unsigned)u) << 16;
  float f;
  __builtin_memcpy(&f, &v, 4);
  return f;
}
__device__ __forceinline__ unsigned short f2bfu(float f) {
  __hip_bfloat16 h = __float2bfloat16(f);  // RNE
  unsigned short u;
  __builtin_memcpy(&u, &h, 2);
  return u;
}
__device__ __forceinline__ unsigned pk2(float a, float b) {
  return (unsigned)f2bfu(a) | ((unsigned)f2bfu(b) << 16);
}

// swap hi 32 lanes of a with lo 32 lanes of b (v_permlane32_swap_b32)
__device__ __forceinline__ void pl32swap(unsigned& a, unsigned& b) {
#if defined(__has_builtin)
#if __has_builtin(__builtin_amdgcn_permlane32_swap)
  typedef int i32x2 __attribute__((ext_vector_type(2)));
  i32x2 r = __builtin_amdgcn_permlane32_swap((int)a, (int)b, false, false);
  a = (unsigned)r[0];
  b = (unsigned)r[1];
  return;
#else
  asm("v_permlane32_swap_b32 %0, %1" : "+v"(a), "+v"(b));
  return;
#endif
#else
  asm("v_permlane32_swap_b32 %0, %1" : "+v"(a), "+v"(b));
#endif
}

// ---------------- dtype probe (proven) ----------------
__global__ __launch_bounds__(256) void probe_dtype(
    const unsigned short* __restrict__ xr, int* __restrict__ flagp) {
  __shared__ int cnt;
  if (threadIdx.x == 0) cnt = 0;
  __syncthreads();
  int bad = 0;
  for (int i = 0; i < 32; ++i) {
    unsigned short u = xr[(threadIdx.x * 32 + i) * 2];
    int e = (u >> 7) & 0xFF;
    if (e == 0xFF || e >= 0x90 || (e != 0 && e <= 0x60)) bad++;
  }
  atomicAdd(&cnt, bad);
  __syncthreads();
  if (threadIdx.x == 0) {
    flagp[0] = (cnt > 512) ? 0 : 1;  // 0=fp32, 1=bf16
    flagp[1] = 1;                    // all-ones-mask flag, cleared by prep
  }
}

// fused preamble: mask->bias (+allones detect), bias_qkv/bias_proj -> f32
__global__ __launch_bounds__(256) void prep(
    const int* __restrict__ am, float* __restrict__ mb,
    int* __restrict__ flagp,
    const void* __restrict__ bq_in, float* __restrict__ bq,
    const void* __restrict__ bp_in, float* __restrict__ bp) {
  int i = blockIdx.x * 256 + threadIdx.x;
  const int flag = flagp[0];
  if (i < 8192) {
    int a = am[i];
    mb[i] = a ? 0.f : NEG_BIG;
    if (a == 0) atomicAnd(flagp + 1, 0);
  } else if (i < 11264) {
    int j = i - 8192;
    bq[j] = (flag == 0) ? ((const float*)bq_in)[j]
                        : bfu2f(((const unsigned short*)bq_in)[j]);
  } else if (i < 12288) {
    int j = i - 11264;
    bp[j] = (flag == 0) ? ((const float*)bp_in)[j]
                        : bfu2f(((const unsigned short*)bp_in)[j]);
  }
}

// x (fp32|bf16) -> bf16, vectorized 8 elems/thread
__global__ __launch_bounds__(256) void conv_x_bf16(
    const void* __restrict__ in, long long off,
    unsigned short* __restrict__ out,
    const int* __restrict__ flagp, int n8) {
  int i = blockIdx.x * 256 + threadIdx.x;
  if (i >= n8) return;
  if (*flagp == 0) {
    const float* p = (const float*)in + off + (size_t)i * 8;
    float4 a = *(const float4*)p;
    float4 b = *(const float4*)(p + 4);
    uint4 o = make_uint4(pk2(a.x, a.y), pk2(a.z, a.w), pk2(b.x, b.y), pk2(b.z, b.w));
    *(uint4*)(out + (size_t)i * 8) = o;
  } else {
    const unsigned short* p = (const unsigned short*)in + off + (size_t)i * 8;
    *(uint4*)(out + (size_t)i * 8) = *(const uint4*)p;
  }
}

// transpose + convert: out_bf16[C][R] = in[R][C]   (proven)
__global__ __launch_bounds__(256) void transpose_conv(
    const void* __restrict__ in, unsigned short* __restrict__ out,
    const int* __restrict__ flagp, int R, int C) {
  __shared__ unsigned short t[32][33];
  const int flag = *flagp;
  const int c0 = blockIdx.x * 32, r0 = blockIdx.y * 32;
  const int lc = threadIdx.x & 31, lr = threadIdx.x >> 5;
  for (int i = 0; i < 4; ++i) {
    int r = lr + i * 8;
    size_t idx = (size_t)(r0 + r) * C + c0 + lc;
    t[r][lc] = (flag == 0) ? f2bfu(((const float*)in)[idx])
                           : ((const unsigned short*)in)[idx];
  }
  __syncthreads();
  for (int i = 0; i < 4; ++i) {
    int r = lr + i * 8;
    out[(size_t)(c0 + r) * R + r0 + lc] = t[lc][r];
  }
}

// -------- unified bf16 GEMM: C = A @ Bt^T + bias -------------------------
// 128x128 tile, BK=64 (32 MFMA per barrier pair), both operands async
// global->LDS, 8-chunk XOR swizzle (ch ^ row&7), XCD-chunked 1D grid.
// bf16 output: staged through dead 32KB LDS, coalesced dwordx4 writes
// (256B/16 lanes).  fp32 output: direct scalar stores (R4-proven).
// NOTE: a 64x128 f32 tile does NOT fit padded in 32KB LDS -- do not stage
// the f32 path (R5 bug: stride 68 < 128 cols aliased rows, absmax 4.8).
__global__ __launch_bounds__(256) void gemm_bb(
    const __hip_bfloat16* __restrict__ A,
    const __hip_bfloat16* __restrict__ Bt,
    const float* __restrict__ bias,
    const int* __restrict__ flagp, int outmode,
    void* __restrict__ Cv, long long coff,
    int M, int N, int K) {
  __shared__ __align__(16) __hip_bfloat16 SH[2][128 * 64];
  __hip_bfloat16* As = SH[0];
  __hip_bfloat16* Bs = SH[1];
  const int flag = *flagp;
  const int tid = threadIdx.x;
  const int lin = blockIdx.x;
  const int mtiles = M >> 7;
  const int mloc = mtiles >> 3;                 // m-tiles per XCD (pow2)
  const int msh = 31 - __builtin_clz(mloc);
  const int xcd = lin & 7, idx = lin >> 3;
  const int m0 = (xcd * mloc + (idx & (mloc - 1))) << 7;
  const int n0 = (idx >> msh) << 7;
  const int w = tid >> 6, lane = tid & 63;
  const int wm = (w & 1) * 64, wn = (w >> 1) * 64;
  const int lm = lane & 15, kg = lane >> 4;

  f32x4 acc[4][4] = {};

  for (int k0 = 0; k0 < K; k0 += 64) {
    __syncthreads();   // readers of LDS done
    #pragma unroll
    for (int c = 0; c < 4; ++c) {
      int o = tid * 16 + c * 4096;
      int row = o >> 7, chp = (o >> 4) & 7;
      int gch = chp ^ (row & 7);
      async_copy16((char*)As + o, (const char*)(A + (size_t)(m0 + row) * K + k0 + gch * 8));
      async_copy16((char*)Bs + o, (const char*)(Bt + (size_t)(n0 + row) * K + k0 + gch * 8));
    }
    __syncthreads();   // staging landed (compiler drains vmcnt before barrier)
    #pragma unroll
    for (int kk = 0; kk < 2; ++kk) {
      bf16x8 af[4], bff[4];
      #pragma unroll
      for (int t = 0; t < 4; ++t) {
        int rt = wm + t * 16 + lm;
        int ch = (kk * 4 + kg) ^ (rt & 7);
        af[t] = *(const bf16x8*)(As + rt * 64 + ch * 8);
        int rb = wn + t * 16 + lm;
        int chb = (kk * 4 + kg) ^ (rb & 7);
        bff[t] = *(const bf16x8*)(Bs + rb * 64 + chb * 8);
      }
      #pragma unroll
      for (int tm = 0; tm < 4; ++tm)
        #pragma unroll
        for (int tn = 0; tn < 4; ++tn)
          acc[tm][tn] = __builtin_amdgcn_mfma_f32_16x16x32_bf16(af[tm], bff[tn], acc[tm][tn], 0, 0, 0);
    }
  }

  const bool f32out = (outmode != 0 && flag == 0);
  if (f32out) {
    // direct scalar stores (proven) -- f32 tile doesn't fit staged in LDS
    for (int tn = 0; tn < 4; ++tn) {
      int col = n0 + wn + tn * 16 + lm;
      float bv = bias[col];
      for (int tm = 0; tm < 4; ++tm) {
        int rbase = m0 + wm + tm * 16 + kg * 4;
        for (int r = 0; r < 4; ++r)
          ((float*)Cv)[(size_t)coff + (size_t)(rbase + r) * N + col] =
              acc[tm][tn][r] + bv;
      }
    }
  } else {
    // bf16: LDS-staged coalesced writes, two 64-row passes (stride 136>127)
    for (int hp = 0; hp < 2; ++hp) {
      __syncthreads();   // prior LDS readers done
      if (wm == hp * 64) {
        __hip_bfloat16* Cs16 = (__hip_bfloat16*)SH;  // stride 136 (272B)
        #pragma unroll
        for (int tn = 0; tn < 4; ++tn) {
          int col = wn + tn * 16 + lm;
          float bv = bias[n0 + col];
          #pragma unroll
          for (int tm = 0; tm < 4; ++tm)
            #pragma unroll
            for (int r = 0; r < 4; ++r)
              Cs16[(tm * 16 + kg * 4 + r) * 136 + col] =
                  __float2bfloat16(acc[tm][tn][r] + bv);
        }
      }
      __syncthreads();
      const __hip_bfloat16* Cs16 = (const __hip_bfloat16*)SH;
      unsigned short* outp = (unsigned short*)Cv + coff;
      #pragma unroll
      for (int rd = 0; rd < 4; ++rd) {
        int chunk = rd * 256 + tid;             // 0..1023
        int row = chunk >> 4, cch = chunk & 15;
        uint4 v = *(const uint4*)(Cs16 + row * 136 + cch * 8);
        *(uint4*)(outp + (size_t)(m0 + hp * 64 + row) * N + n0 + cch * 8) = v;
      }
    }
  }
}

// -------- causal flash attention v5 (proven R2 config) ---------------------
// 256 threads (4 waves), 128 q/block (32 q/wave), 32-key subtiles.
// K fetched DIRECTLY global->VGPR as MFMA A-fragments, software-pipelined
// one subtile ahead (ka/kb parity) -- no K LDS, no K barrier coupling.
// Only V goes through LDS (transposed, double-buffered, 1 barrier/tile).
// XCD-chunked block swizzle keeps each (b,h)'s K/V panels L2-hot.
// NOTE: do NOT shrink blocks / raise launch_bounds min-waves: the 128-thread
// (128,4) variant spilled (~470 MB scratch writes, 2.5x slower).
#define VSTR 72
__device__ __forceinline__ void attn_subtile(
    int j0s, int wq_min, int wq_max, int qg, int allones,
    const char* kbyte, const float* mbrow,
    uint4& kc0, uint4& kc1, uint4& kc2, uint4& kc3,
    uint4& kn0, uint4& kn1, uint4& kn2, uint4& kn3,
    const bf16x8* bq, const __hip_bfloat16* VTb, int hi,
    float& mrow, float& plocal, f32x16& o0, f32x16& o1) {
  if (j0s > wq_max) return;
  {  // prefetch next subtile's K fragments (registers)
    const int jn = j0s + 32;
    if (jn <= wq_max) {
      const char* kp = kbyte + (size_t)jn * 6144;
      kn0 = *(const uint4*)(kp);
      kn1 = *(const uint4*)(kp + 32);
      kn2 = *(const uint4*)(kp + 64);
      kn3 = *(const uint4*)(kp + 96);
    }
  }
  bf16x8 a0, a1, a2, a3;
  __builtin_memcpy(&a0, &kc0, 16);
  __builtin_memcpy(&a1, &kc1, 16);
  __builtin_memcpy(&a2, &kc2, 16);
  __builtin_memcpy(&a3, &kc3, 16);

  // ---- S^T = K · Q^T ----
  f32x16 sacc = {};
  __builtin_amdgcn_s_setprio(1);
  sacc = __builtin_amdgcn_mfma_f32_32x32x16_bf16(a0, bq[0], sacc, 0, 0, 0);
  sacc = __builtin_amdgcn_mfma_f32_32x32x16_bf16(a1, bq[1], sacc, 0, 0, 0);
  sacc = __builtin_amdgcn_mfma_f32_32x32x16_bf16(a2, bq[2], sacc, 0, 0, 0);
  sacc = __builtin_amdgcn_mfma_f32_32x32x16_bf16(a3, bq[3], sacc, 0, 0, 0);
  __builtin_amdgcn_s_setprio(0);

  // ---- mask + max ----
  float mt = NEG_BIG;
  const bool needc = (j0s + 31 > wq_min);
  if (allones) {
    if (needc) {
      #pragma unroll
      for (int r = 0; r < 16; ++r) {
        int key = j0s + (r & 3) + 8 * (r >> 2) + 4 * hi;
        float v = (key <= qg) ? sacc[r] : NEG_BIG;
        sacc[r] = v;
        mt = fmaxf(mt, v);
      }
    } else {
      #pragma unroll
      for (int r = 0; r < 16; ++r) mt = fmaxf(mt, sacc[r]);
    }
    mt *= SC2;  // scores stay raw; scale folded into exp fma
  } else {
    #pragma unroll
    for (int rr = 0; rr < 4; ++rr) {
      float4 mb4 = *(const float4*)(mbrow + j0s + rr * 8 + hi * 4);
      const float* mp = (const float*)&mb4;
      #pragma unroll
      for (int i = 0; i < 4; ++i) {
        int r = rr * 4 + i;
        int key = j0s + i + 8 * rr + 4 * hi;
        float v = fmaf(sacc[r], SC2, mp[i]);
        if (needc) v = (key <= qg) ? v : NEG_BIG;
        sacc[r] = v;
        mt = fmaxf(mt, v);
      }
    }
  }
  mt = fmaxf(mt, __shfl_xor(mt, 32));

  // ---- defer-max rescale (THR=8, log2 domain) ----
  if (!__all(mt <= mrow + 8.f)) {
    float mn = fmaxf(mrow, mt);
    float a = __builtin_exp2f(mrow - mn);
    plocal *= a;
    #pragma unroll
    for (int r = 0; r < 16; ++r) { o0[r] *= a; o1[r] *= a; }
    mrow = mn;
  }

  // ---- exp + pack ----
  const float sfac = allones ? SC2 : 1.0f;
  float psl = 0.f;
  unsigned pk[8];
  #pragma unroll
  for (int r2 = 0; r2 < 8; ++r2) {
    float p0 = __builtin_exp2f(fmaf(sacc[2 * r2],     sfac, -mrow));
    float p1 = __builtin_exp2f(fmaf(sacc[2 * r2 + 1], sfac, -mrow));
    psl += p0 + p1;
    pk[r2] = pk2(p0, p1);
  }
  plocal += psl;

  // ---- in-register P exchange ----
  pl32swap(pk[0], pk[2]);
  pl32swap(pk[1], pk[3]);
  pl32swap(pk[4], pk[6]);
  pl32swap(pk[5], pk[7]);

  // ---- O^T += V^T · P ----
  __builtin_amdgcn_s_setprio(1);
  #pragma unroll
  for (int ks = 0; ks < 2; ++ks) {
    uint4 t = make_uint4(pk[ks * 4 + 0], pk[ks * 4 + 1],
                         pk[ks * 4 + 2], pk[ks * 4 + 3]);
    bf16x8 bp;
    __builtin_memcpy(&bp, &t, 16);
    bf16x8 av0 = *(const bf16x8*)(VTb + ks * 16);
    bf16x8 av1 = *(const bf16x8*)(VTb + 32 * VSTR + ks * 16);
    o0 = __builtin_amdgcn_mfma_f32_32x32x16_bf16(av0, bp, o0, 0, 0, 0);
    o1 = __builtin_amdgcn_mfma_f32_32x32x16_bf16(av1, bp, o1, 0, 0, 0);
  }
  __builtin_amdgcn_s_setprio(0);
}

__global__ __launch_bounds__(256, 3) void attn_flash(
    const __hip_bfloat16* __restrict__ qkv,  // [bsz*S][3072]
    const float* __restrict__ mbias,         // [bsz*S] 0 / -1e30
    const int* __restrict__ flags,           // flags[1]: mask all-ones
    __hip_bfloat16* __restrict__ outp) {     // [bsz*S][1024]
  __shared__ __align__(16) __hip_bfloat16 VT[2][64 * VSTR]; // [d][key]

  const int tid = threadIdx.x;
  // XCD-chunked swizzle: XCD k owns bh in [k*bhloc,(k+1)*bhloc), all q-tiles;
  // within XCD, heavy q-tiles (large qt) dispatched first (LPT).
  const int lin = blockIdx.x;
  const int nbh = gridDim.x >> 4;          // 16 q-blocks of 128 rows
  const int bhloc = nbh >> 3;
  const int bsh = 31 - __builtin_clz(bhloc);
  const int xcd = lin & 7, idx = lin >> 3;
  const int bh = xcd * bhloc + (idx & (bhloc - 1));
  const int bx = idx >> bsh;
  const int qt = 15 - bx;                  // LPT: heavy first
  const int b = bh >> 4, h = bh & 15;
  const int q0 = qt * 128;
  const size_t rowbase = (size_t)b * S_;
  const int w = tid >> 6, lane = tid & 63;
  const int l31 = lane & 31, hi = lane >> 5;
  const int qg = q0 + w * 32 + l31;
  const int wq_min = q0 + w * 32, wq_max = wq_min + 31;
  const int allones = flags[1];
  const float* mbrow = mbias + rowbase;

  // per-lane K base: row l31, d-offset hi*8 (fragment kc at +kc*32B)
  const char* kbyte = (const char*)(qkv + (rowbase + l31) * 3072 + 1024 + h * 64 + hi * 8);

  // Q fragments: lane holds Q[qg][kc*16 + hi*8 + e]
  bf16x8 bq[4];
  {
    const __hip_bfloat16* qp = qkv + (rowbase + qg) * 3072 + h * 64 + hi * 8;
    bq[0] = *(const bf16x8*)(qp);
    bq[1] = *(const bf16x8*)(qp + 16);
    bq[2] = *(const bf16x8*)(qp + 32);
    bq[3] = *(const bf16x8*)(qp + 48);
  }

  const int jmax = 2 * qt + 1;

  // prologue: K subtile 0 into ka; V tile 0 into VT[0]
  uint4 ka0, ka1, ka2, ka3, kb0, kb1, kb2, kb3;
  ka0 = *(const uint4*)(kbyte);
  ka1 = *(const uint4*)(kbyte + 32);
  ka2 = *(const uint4*)(kbyte + 64);
  ka3 = *(const uint4*)(kbyte + 96);
  {
    const __hip_bfloat16* vp = qkv + (rowbase + lane) * 3072 + 2048 + h * 64 + w * 16;
    uint4 v0 = *(const uint4*)(vp);
    uint4 v1 = *(const uint4*)(vp + 8);
    const __hip_bfloat16* p0 = (const __hip_bfloat16*)&v0;
    const __hip_bfloat16* p1 = (const __hip_bfloat16*)&v1;
    #pragma unroll
    for (int e = 0; e < 8; ++e) {
      VT[0][(w * 16 + e) * VSTR + lane] = p0[e];
      VT[0][(w * 16 + 8 + e) * VSTR + lane] = p1[e];
    }
  }

  float mrow = NEG_BIG, plocal = 0.f;
  f32x16 o0 = {}, o1 = {};   // O^T: col q=l31, row d = dblk*32 + (r&3)+8*(r>>2)+4*hi
  int buf = 0;

  for (int j = 0; j <= jmax; ++j) {
    __syncthreads();  // VT[buf] staged; prior readers of nbuf done
    const int nbuf = buf ^ 1;
    const int j0 = j * 64;
    const bool pre = (j < jmax);
    uint4 vva, vvb;
    if (pre) {
      const __hip_bfloat16* vp = qkv + (rowbase + j0 + 64 + lane) * 3072 + 2048 + h * 64 + w * 16;
      vva = *(const uint4*)(vp);
      vvb = *(const uint4*)(vp + 8);
    }
    const __hip_bfloat16* vb0 = VT[buf] + l31 * VSTR + hi * 8;

    attn_subtile(j0, wq_min, wq_max, qg, allones, kbyte, mbrow,
                 ka0, ka1, ka2, ka3, kb0, kb1, kb2, kb3,
                 bq, vb0, hi, mrow, plocal, o0, o1);
    attn_subtile(j0 + 32, wq_min, wq_max, qg, allones, kbyte, mbrow,
                 kb0, kb1, kb2, kb3, ka0, ka1, ka2, ka3,
                 bq, vb0 + 32, hi, mrow, plocal, o0, o1);

    if (pre) {  // finish staging of nbuf (VT)
      const __hip_bfloat16* p0 = (const __hip_bfloat16*)&vva;
      const __hip_bfloat16* p1 = (const __hip_bfloat16*)&vvb;
      #pragma unroll
      for (int e = 0; e < 8; ++e) {
        VT[nbuf][(w * 16 + e) * VSTR + lane] = p0[e];
        VT[nbuf][(w * 16 + 8 + e) * VSTR + lane] = p1[e];
      }
    }
    buf = nbuf;
  }

  {  // epilogue: reduce l across hi halves, divide, store
    float l = plocal + __shfl_xor(plocal, 32);
    float linv = (l > 0.f) ? 1.f / l : 0.f;
    __hip_bfloat16* ob = outp + (rowbase + qg) * 1024 + h * 64;
    #pragma unroll
    for (int rr = 0; rr < 4; ++rr) {
      bf16x4v ov;
      ov[0] = (__bf16)(o0[rr * 4 + 0] * linv);
      ov[1] = (__bf16)(o0[rr * 4 + 1] * linv);
      ov[2] = (__bf16)(o0[rr * 4 + 2] * linv);
      ov[3] = (__bf16)(o0[rr * 4 + 3] * linv);
      *(bf16x4v*)(ob + rr * 8 + hi * 4) = ov;
      bf16x4v ow;
      ow[0] = (__bf16)(o1[rr * 4 + 0] * linv);
      ow[1] = (__bf16)(o1[rr * 4 + 1] * linv);
      ow[2] = (__bf16)(o1[rr * 4 + 2] * linv);
      ow[3] = (__bf16)(o1[rr * 4 + 3] * linv);
      *(bf16x4v*)(ob + 32 + rr * 8 + hi * 4) = ow;
    }
  }
}

extern "C" void kernel_launch(void* const* d_in, const int* in_sizes, int n_in,
                              void* d_out, int out_size, void* d_ws, size_t ws_size,
                              hipStream_t stream) {
  const bool merged = (ws_size >= (80ull << 20));
  char* ws = (char*)d_ws;
  int*            flag   = (int*)ws;
  float*          bq     = (float*)(ws + 1024);
  float*          bp     = (float*)(ws + 16384);
  float*          mbias  = (float*)(ws + 32768);
  unsigned short* WqkvTu = (unsigned short*)(ws + 65536);
  unsigned short* WprojTu= (unsigned short*)(ws + 65536 + 6291456);
  char*           big    = ws + 65536 + 8388608;
  __hip_bfloat16* qkv    = (__hip_bfloat16*)big;
  // attno region doubles as xbf (x pre-converted to bf16): xbf is consumed
  // by GEMM1 before attn writes attno over it.
  char*           anx    = big + (merged ? 50331648u : 12582912u);
  __hip_bfloat16* attno  = (__hip_bfloat16*)anx;
  unsigned short* xbf    = (unsigned short*)anx;

  probe_dtype<<<1, 256, 0, stream>>>((const unsigned short*)d_in[0], flag);
  prep<<<48, 256, 0, stream>>>((const int*)d_in[1], mbias, flag,
                               d_in[3], bq, d_in[5], bp);
  transpose_conv<<<dim3(96, 32), 256, 0, stream>>>(d_in[2], WqkvTu, flag, 1024, 3072);
  transpose_conv<<<dim3(32, 32), 256, 0, stream>>>(d_in[4], WprojTu, flag, 1024, 1024);

  const int nchunk = merged ? 1 : B_;
  const int bsz = merged ? B_ : 1;
  const int Mc = bsz * S_;
  for (int c = 0; c < nchunk; ++c) {
    long long off = (long long)c * S_ * E_;
    conv_x_bf16<<<dim3((Mc * 1024) / 2048), 256, 0, stream>>>(
        d_in[0], off, xbf, flag, (Mc * 1024) / 8);
    gemm_bb<<<dim3((Mc / 128) * (3072 / 128)), 256, 0, stream>>>(
        (const __hip_bfloat16*)xbf, (const __hip_bfloat16*)WqkvTu, bq, flag, 0,
        qkv, 0, Mc, 3072, 1024);
    attn_flash<<<dim3((S_ / 128) * (bsz * H_)), 256, 0, stream>>>(
        qkv, mbias + (size_t)c * S_, flag, attno);
    gemm_bb<<<dim3((Mc / 128) * (1024 / 128)), 256, 0, stream>>>(
        attno, (const __hip_bfloat16*)WprojTu, bp, flag, 1,
        d_out, off, Mc, 1024, 1024);
  }
}